// Round 1
// baseline (51.324 us; speedup 1.0000x reference)
//
#include <hip/hip_runtime.h>
#include <math.h>

#define H_ 768
#define W_ 768
#define TY 16
#define TX 64
#define NTHREADS 256
#define EPS_ 1e-6f

__device__ __forceinline__ int refl(int c, int n) {
    c = c < 0 ? -c : c;
    c = c >= n ? 2 * n - 2 - c : c;
    return c;
}

__global__ __launch_bounds__(NTHREADS)
void bayer_feat(const float* __restrict__ in, float* __restrict__ out) {
    const int bz  = blockIdx.z;
    const int gy0 = blockIdx.y * TY;
    const int gx0 = blockIdx.x * TX;
    const int tid = threadIdx.x;
    const float* src = in + (size_t)bz * (H_ * W_);

    __shared__ float sB[TY + 6][TX + 7];          // bayer tile, halo 3 (reflect-mapped)
    __shared__ float sE[7][TY + 2][TX + 2];       // gx, gy, hgh, hgv, chk, stx, sty (halo 1)

    // ---- stage bayer tile with reflect mapping ----
    for (int i = tid; i < (TY + 6) * (TX + 6); i += NTHREADS) {
        int r = i / (TX + 6), c = i - r * (TX + 6);
        sB[r][c] = src[refl(gy0 - 3 + r, H_) * W_ + refl(gx0 - 3 + c, W_)];
    }
    __syncthreads();

    // ---- first-stage fields on halo-1 extended tile ----
    // For out-of-image extended coords, evaluate the conv AT the reflected
    // coordinate (that is exactly what reflect-padding of the field means).
    for (int i = tid; i < (TY + 2) * (TX + 2); i += NTHREADS) {
        int ey = i / (TX + 2), ex = i - ey * (TX + 2);
        int sy = refl(gy0 - 1 + ey, H_) - gy0 + 3;
        int sx = refl(gx0 - 1 + ex, W_) - gx0 + 3;
        float a00 = sB[sy-1][sx-1], a01 = sB[sy-1][sx], a02 = sB[sy-1][sx+1];
        float a10 = sB[sy  ][sx-1], a11 = sB[sy  ][sx], a12 = sB[sy  ][sx+1];
        float a20 = sB[sy+1][sx-1], a21 = sB[sy+1][sx], a22 = sB[sy+1][sx+1];
        float l2 = sB[sy][sx-2], r2 = sB[sy][sx+2];
        float u2 = sB[sy-2][sx], d2 = sB[sy+2][sx];
        sE[0][ey][ex] = 0.125f * (-a00 + a02 - 2.f*a10 + 2.f*a12 - a20 + a22);        // gx (sobel_x)
        sE[1][ey][ex] = 0.125f * (-a00 - 2.f*a01 - a02 + a20 + 2.f*a21 + a22);        // gy (sobel_y)
        sE[2][ey][ex] = -0.25f*(l2 + r2) + 0.5f*(a10 + a11 + a12);                    // hgh
        sE[3][ey][ex] = -0.25f*(u2 + d2) + 0.5f*(a01 + a11 + a21);                    // hgv
        sE[4][ey][ex] = (a00 - a01 + a02 - a10 + a11 - a12 + a20 - a21 + a22) * (1.f/9.f); // chk
        sE[5][ey][ex] = 0.25f*(l2 + r2) - (a10 + a12) + 1.5f*a11;                     // stx
        sE[6][ey][ex] = 0.25f*(u2 + d2) - (a01 + a21) + 1.5f*a11;                     // sty
    }
    __syncthreads();

    const int tx = tid & 63;
    const int ty = tid >> 6;
    const size_t HW = (size_t)H_ * W_;
    float* outb = out + (size_t)bz * 52 * HW;

    // gabor(pi/4) coefficients (mean-subtracted, L1-normalized), [ky][kx]
    const float G45[5][5] = {
        {-0.002092f, -0.015195f, -0.063321f, -0.002285f,  0.036511f},
        {-0.015195f, -0.086304f,  0.003803f,  0.119456f, -0.002285f},
        {-0.063321f,  0.003803f,  0.172851f,  0.003803f, -0.063321f},
        {-0.002285f,  0.119456f,  0.003803f, -0.086304f, -0.015195f},
        { 0.036511f, -0.002285f, -0.063321f, -0.015195f, -0.002092f}
    };
    // dct_like(u=2,v=2,5) is separable: outer(ADC, ADC)
    const float ADC[5] = {0.25f, -0.09549150f, -0.30901699f, -0.09549150f, 0.25f};
    const float inv9 = 1.f / 9.f;

    for (int k = 0; k < 4; ++k) {
        const int ly = ty * 4 + k;
        const int lx = tx;
        const int gy = gy0 + ly, gx = gx0 + lx;
        const int sy = ly + 3, sx = lx + 3;
        const int ey = ly + 1, ex = lx + 1;
        const int py = gy & 1, px = gx & 1;

        float a[5][5];
#pragma unroll
        for (int dy = 0; dy < 5; ++dy)
#pragma unroll
            for (int dx = 0; dx < 5; ++dx)
                a[dy][dx] = sB[sy - 2 + dy][sx - 2 + dx];

#define A_(dy, dx) a[(dy) + 2][(dx) + 2]
        float* po = outb + (size_t)gy * W_ + gx;
#define ST(c, v) po[(size_t)(c) * HW] = (v)

        // 0..6: masks (gbrg)
        ST(0, (float)(py & (px ^ 1)));          // r: odd row, even col
        ST(1, (float)(py == px));               // g = gr + gb
        ST(2, (float)((py ^ 1) & px));          // b: even row, odd col
        ST(3, (float)(py & px));                // gr
        ST(4, (float)((py ^ 1) & (px ^ 1)));    // gb
        ST(5, (float)py);                       // row
        ST(6, (float)px);                       // col

        // 3x3 stencils at center
        float lap = A_(-1,0) + A_(0,-1) - 4.f*A_(0,0) + A_(0,1) + A_(1,0);
        float hxx = A_(0,-1) - 2.f*A_(0,0) + A_(0,1);
        float hyy = A_(-1,0) - 2.f*A_(0,0) + A_(1,0);
        float hxy = 0.25f*(A_(-1,-1) - A_(-1,1) - A_(1,-1) + A_(1,1));
        ST(7, lap); ST(8, hxx); ST(9, hyy); ST(10, hxy);

        // morphological gradient 3x3
        float mxv = A_(-1,-1), mnv = A_(-1,-1);
#pragma unroll
        for (int dy = -1; dy <= 1; ++dy)
#pragma unroll
            for (int dx = -1; dx <= 1; ++dx) {
                float v = A_(dy, dx);
                mxv = fmaxf(mxv, v); mnv = fminf(mnv, v);
            }
        ST(11, mxv - mnv);

        float gxv = sE[0][ey][ex], gyv = sE[1][ey][ex];
        ST(12, gxv); ST(13, gyv);
        float gdm = 0.125f*(-2.f*A_(-1,-1) - A_(-1,0) - A_(0,-1) + A_(0,1) + A_(1,0) + 2.f*A_(1,1));
        float gda = 0.125f*(A_(-1,0) + 2.f*A_(-1,1) - A_(0,-1) + A_(0,1) - 2.f*A_(1,-1) - A_(1,0));
        ST(14, gdm); ST(15, gda);
        ST(16, sqrtf(gxv*gxv + gyv*gyv + EPS_));

        // second-stage 3x3 box filters over ext fields
        float jxx = 0.f, jyy = 0.f, jxy = 0.f, reh = 0.f, rev = 0.f, cke = 0.f, ste = 0.f;
#pragma unroll
        for (int dy = -1; dy <= 1; ++dy)
#pragma unroll
            for (int dx = -1; dx <= 1; ++dx) {
                float gxn = sE[0][ey+dy][ex+dx];
                float gyn = sE[1][ey+dy][ex+dx];
                jxx += gxn*gxn; jyy += gyn*gyn; jxy += gxn*gyn;
                float bn = A_(dy, dx);
                float rh = bn - sE[2][ey+dy][ex+dx];
                float rv = bn - sE[3][ey+dy][ex+dx];
                reh += rh*rh; rev += rv*rv;
                float ckn = sE[4][ey+dy][ex+dx];
                cke += ckn*ckn;
                float sxn = sE[5][ey+dy][ex+dx], syn = sE[6][ey+dy][ex+dx];
                ste += sxn*sxn + syn*syn;
            }
        jxx *= inv9; jyy *= inv9; jxy *= inv9;
        float trc = jxx + jyy;
        float lam = sqrtf((jxx - jyy)*(jxx - jyy) + 4.f*jxy*jxy + EPS_);
        ST(17, lam / (trc + EPS_));
        ST(18, (jxx - jyy) / (trc + EPS_));

        float hsh = -0.5f*(A_(0,-2) + A_(0,2)) + A_(0,0);
        float hsv = -0.5f*(A_(-2,0) + A_(2,0)) + A_(0,0);
        ST(19, hsh); ST(20, hsv);
        float hghv = sE[2][ey][ex], hgvv = sE[3][ey][ex];
        ST(21, hghv); ST(22, hgvv);
        ST(23, fabsf(hghv - hgvv));
        float ctr = A_(0,0);
        ST(24, ctr - hghv); ST(25, ctr - hgvv);
        ST(26, reh * inv9); ST(27, rev * inv9);
        ST(28, fabsf(gxv) - fabsf(gyv));
        ST(29, fabsf(hxx) - fabsf(hyy));

        // 1x5 / 5x1 line variances
        float sh = A_(0,-2)+A_(0,-1)+A_(0,0)+A_(0,1)+A_(0,2);
        float qh = A_(0,-2)*A_(0,-2)+A_(0,-1)*A_(0,-1)+A_(0,0)*A_(0,0)+A_(0,1)*A_(0,1)+A_(0,2)*A_(0,2);
        float sv = A_(-2,0)+A_(-1,0)+A_(0,0)+A_(1,0)+A_(2,0);
        float qv = A_(-2,0)*A_(-2,0)+A_(-1,0)*A_(-1,0)+A_(0,0)*A_(0,0)+A_(1,0)*A_(1,0)+A_(2,0)*A_(2,0);
        float mh = sh * 0.2f, mv = sv * 0.2f;
        float lvh = fmaxf(qh*0.2f - mh*mh, 0.f);
        float lvv = fmaxf(qv*0.2f - mv*mv, 0.f);
        ST(30, lvh); ST(31, lvv);
        float lvd = lvh - lvv;
        ST(32, lvd);
        ST(33, fabsf(lvd) / (lvh + lvv + EPS_));

        // normalized sparse fills: smooth5(bayer*mask)/smooth5(mask)
        // reflect preserves parity -> den is a pure parity function.
        float cEE, cOE, cEO, cOO;
        {
            float rEv[5], rOv[5];
#pragma unroll
            for (int dy = 0; dy < 5; ++dy) {
                float e0 = a[dy][0] + 3.f*a[dy][2] + a[dy][4];   // even dx taps (w 1,3,1)
                float e1 = 2.f*(a[dy][1] + a[dy][3]);            // odd  dx taps (w 2,2)
                rEv[dy] = px ? e1 : e0;   // taps where (gx+dx) even
                rOv[dy] = px ? e0 : e1;   // taps where (gx+dx) odd
            }
            float t0 = rEv[0] + 3.f*rEv[2] + rEv[4];
            float t1 = 2.f*(rEv[1] + rEv[3]);
            float t2 = rOv[0] + 3.f*rOv[2] + rOv[4];
            float t3 = 2.f*(rOv[1] + rOv[3]);
            cEE = py ? t1 : t0;   // (y even, x even) numerator*81
            cOE = py ? t0 : t1;   // (y odd , x even)
            cEO = py ? t3 : t2;   // (y even, x odd )
            cOO = py ? t2 : t3;   // (y odd , x odd )
        }
        float Sy_e = py ? 4.f : 5.f, Sx_e = px ? 4.f : 5.f;
        float Sy_o = 9.f - Sy_e,     Sx_o = 9.f - Sx_e;
        float rfv  = cOE / (Sy_o * Sx_e);
        float bfv  = cEO / (Sy_e * Sx_o);
        float grfv = cOO / (Sy_o * Sx_o);
        float gbfv = cEE / (Sy_e * Sx_e);
        float gfv  = (cEE + cOO) / (Sy_e * Sx_e + Sy_o * Sx_o);
        ST(34, rfv - gfv);
        ST(35, bfv - gfv);
        ST(36, grfv - gbfv);

        float mhcf = 0.125f*(-A_(-2,0) + 2.f*A_(-1,0) - A_(0,-2) + 2.f*A_(0,-1) + 4.f*A_(0,0)
                             + 2.f*A_(0,1) - A_(0,2) + 2.f*A_(1,0) - A_(2,0));
        float mhc = (py == px) ? ctr : mhcf;
        ST(37, mhc);
        ST(38, mhc - 0.5f*(hghv + hgvv));
        ST(39, (py & (px ^ 1)) ? (ctr - mhc) : 0.f);
        ST(40, ((py ^ 1) & px) ? (ctr - mhc) : 0.f);

        ST(41, sE[5][ey][ex]); ST(42, sE[6][ey][ex]); ST(43, sE[4][ey][ex]);

        float s45 = 0.f, s135 = 0.f;
#pragma unroll
        for (int dy = 0; dy < 5; ++dy)
#pragma unroll
            for (int dx = 0; dx < 5; ++dx) {
                s45  += G45[dy][dx]     * a[dy][dx];
                s135 += G45[dy][4 - dx] * a[dy][dx];   // gabor(3pi/4) = x-flip of gabor(pi/4)
            }
        ST(44, s45); ST(45, s135);

        float dctp = 0.f;
#pragma unroll
        for (int dy = 0; dy < 5; ++dy) {
            float t = ADC[0]*a[dy][0] + ADC[1]*a[dy][1] + ADC[2]*a[dy][2] + ADC[3]*a[dy][3] + ADC[4]*a[dy][4];
            dctp += ADC[dy] * t;
        }
        ST(46, dctp);

        ST(47, cke * inv9);
        ST(48, ste * inv9);

        float s3 = 0.f, q3 = 0.f;
#pragma unroll
        for (int dy = -1; dy <= 1; ++dy)
#pragma unroll
            for (int dx = -1; dx <= 1; ++dx) { float v = A_(dy, dx); s3 += v; q3 += v*v; }
        float lmean = s3 * inv9;
        ST(49, lmean);
        ST(50, fmaxf(q3 * inv9 - lmean*lmean, 0.f));
        ST(51, trc);   // gen = avg3(gx^2+gy^2) = jxx + jyy

#undef A_
#undef ST
    }
}

extern "C" void kernel_launch(void* const* d_in, const int* in_sizes, int n_in,
                              void* d_out, int out_size, void* d_ws, size_t ws_size,
                              hipStream_t stream) {
    (void)n_in; (void)d_ws; (void)ws_size; (void)out_size;
    const float* bayer = (const float*)d_in[0];
    float* out = (float*)d_out;
    const int B = in_sizes[0] / (H_ * W_);
    dim3 grid(W_ / TX, H_ / TY, B);
    bayer_feat<<<grid, NTHREADS, 0, stream>>>(bayer, out);
}